// Round 1
// baseline (2709.980 us; speedup 1.0000x reference)
//
#include <hip/hip_runtime.h>
#include <hip/hip_bf16.h>
#include <math.h>

#define HN 12
#define DH 64
#define WW 256
#define GG 16
#define BB 2
#define SS 4096
#define DD 768
#define NTOK (BB*SS)        // 8192
#define NCHUNK (SS/WW)      // 16

// ---------------- embedding gather ----------------
__global__ void k_gather(const int* __restrict__ ids, const float* __restrict__ emb,
                         float* __restrict__ x) {
    int row = blockIdx.x;                    // 0..NTOK-1
    int id = ids[row];
    const float4* src = (const float4*)(emb + (size_t)id * DD);
    float4* dst = (float4*)(x + (size_t)row * DD);
    for (int j = threadIdx.x; j < DD/4; j += blockDim.x) dst[j] = src[j];
}

// ---------------- f32 tiled GEMM: C[M x 768] = A[M x 768] @ Wm[768 x 768] + bias, then *scale
#define BM 64
#define BN 64
#define BKK 16
__global__ __launch_bounds__(256) void k_gemm(const float* __restrict__ A,
                                              const float* __restrict__ Wm,
                                              const float* __restrict__ bias,
                                              float* __restrict__ C,
                                              float scale) {
    __shared__ float As[BKK][BM+1];
    __shared__ float Bs[BKK][BN+1];
    int bm = blockIdx.y, bn = blockIdx.x;
    int tid = threadIdx.x;
    int tr = tid >> 4, tc = tid & 15;      // 16x16 threads, 4x4 micro-tile
    float acc[4][4] = {};
    int row0 = bm*BM, col0 = bn*BN;
    for (int k0 = 0; k0 < DD; k0 += BKK) {
        for (int i = tid; i < BM*BKK; i += 256) {
            int r = i / BKK, c = i % BKK;
            As[c][r] = A[(size_t)(row0 + r)*DD + k0 + c];
        }
        for (int i = tid; i < BKK*BN; i += 256) {
            int r = i / BN, c = i % BN;
            Bs[r][c] = Wm[(size_t)(k0 + r)*DD + col0 + c];
        }
        __syncthreads();
        #pragma unroll
        for (int kk = 0; kk < BKK; ++kk) {
            float a[4], b[4];
            #pragma unroll
            for (int i = 0; i < 4; ++i) a[i] = As[kk][tr*4+i];
            #pragma unroll
            for (int j = 0; j < 4; ++j) b[j] = Bs[kk][tc*4+j];
            #pragma unroll
            for (int i = 0; i < 4; ++i)
                #pragma unroll
                for (int j = 0; j < 4; ++j) acc[i][j] += a[i]*b[j];
        }
        __syncthreads();
    }
    #pragma unroll
    for (int i = 0; i < 4; ++i)
        #pragma unroll
        for (int j = 0; j < 4; ++j) {
            int r = row0 + tr*4 + i, cc = col0 + tc*4 + j;
            C[(size_t)r*DD + cc] = (acc[i][j] + bias[cc]) * scale;
        }
}

// ---------------- qg projection: 32 rows (b*16+g) of x @ Wqg + bqg, *0.125
__global__ void k_qg(const float* __restrict__ x, const float* __restrict__ Wqg,
                     const float* __restrict__ bqg, float* __restrict__ qg) {
    int col = blockIdx.x * 64 + threadIdx.x;   // 0..767
    int r = blockIdx.y;                        // 0..31
    int b = r / GG, g = r % GG;
    const float* xr = x + (size_t)(b*SS + g)*DD;
    float acc = 0.f;
    for (int d = 0; d < DD; ++d) acc += xr[d] * Wqg[(size_t)d*DD + col];
    qg[r*DD + col] = (acc + bqg[col]) * 0.125f;
}

// ---------------- global-token full attention: one block per (b,h,g)
__global__ __launch_bounds__(256) void k_gattn(const float* __restrict__ qg,
                                               const float* __restrict__ kg,
                                               const float* __restrict__ vg,
                                               float* __restrict__ gctx) {
    int bid = blockIdx.x;                 // b*H*G + h*G + g
    int b = bid / (HN*GG);
    int h = (bid / GG) % HN;
    int g = bid % GG;
    int tid = threadIdx.x;
    __shared__ float qrow[DH];
    __shared__ float sc[SS];              // 16 KB
    __shared__ float red[256];
    __shared__ float part[4][DH];
    if (tid < DH) qrow[tid] = qg[(size_t)(b*GG + g)*DD + h*DH + tid];
    __syncthreads();
    float lmax = -1e30f;
    for (int s = tid; s < SS; s += 256) {
        const float* kr = kg + ((size_t)(b*SS + s)*DD + h*DH);
        float dot = 0.f;
        #pragma unroll
        for (int d = 0; d < DH; ++d) dot += qrow[d]*kr[d];
        sc[s] = dot;
        lmax = fmaxf(lmax, dot);
    }
    red[tid] = lmax; __syncthreads();
    for (int st = 128; st > 0; st >>= 1) { if (tid < st) red[tid] = fmaxf(red[tid], red[tid+st]); __syncthreads(); }
    float m = red[0];
    __syncthreads();
    float lsum = 0.f;
    for (int s = tid; s < SS; s += 256) { float p = expf(sc[s]-m); sc[s] = p; lsum += p; }
    red[tid] = lsum; __syncthreads();
    for (int st = 128; st > 0; st >>= 1) { if (tid < st) red[tid] += red[tid+st]; __syncthreads(); }
    float inv = 1.0f / red[0];
    int dh = tid & 63, s4 = tid >> 6;
    float acc = 0.f;
    for (int s = s4; s < SS; s += 4) acc += sc[s] * vg[((size_t)(b*SS+s)*DD + h*DH + dh)];
    part[s4][dh] = acc;
    __syncthreads();
    if (tid < DH) {
        float r2 = (part[0][tid]+part[1][tid]+part[2][tid]+part[3][tid]) * inv;
        gctx[((size_t)((b*HN + h)*GG + g))*DH + tid] = r2;
    }
}

// ---------------- sliding-window + global-key attention: one block per (b,h,chunk)
__global__ __launch_bounds__(256) void k_wattn(const float* __restrict__ q,
                                               const float* __restrict__ k,
                                               const float* __restrict__ v,
                                               float* __restrict__ ctx) {
    int bid = blockIdx.x;                 // b*H*NCHUNK + h*NCHUNK + ci
    int b = bid / (HN*NCHUNK);
    int h = (bid / NCHUNK) % HN;
    int ci = bid % NCHUNK;
    int tid = threadIdx.x;
    int qpos = ci*WW + tid;

    float qr[DH];
    const float* qsrc = q + ((size_t)(b*SS + qpos)*DD + h*DH);
    #pragma unroll
    for (int d = 0; d < DH; ++d) qr[d] = qsrc[d];

    float m = -1e30f, l = 0.f;
    float acc[DH];
    #pragma unroll
    for (int d = 0; d < DH; ++d) acc[d] = 0.f;

    __shared__ float kt[64][DH];
    __shared__ float vt[64][DH];

    // ---- 16 global keys (kpos 0..15), unmasked for every query ----
    for (int i = tid; i < GG*DH; i += 256) {
        int r = i / DH, d2 = i % DH;
        kt[r][d2] = k[((size_t)(b*SS + r)*DD + h*DH + d2)];
        vt[r][d2] = v[((size_t)(b*SS + r)*DD + h*DH + d2)];
    }
    __syncthreads();
    for (int j = 0; j < GG; ++j) {
        float dot = 0.f;
        #pragma unroll
        for (int d = 0; d < DH; ++d) dot += qr[d]*kt[j][d];
        float mn = fmaxf(m, dot);
        float corr = expf(m - mn);
        float p = expf(dot - mn);
        l = l*corr + p;
        #pragma unroll
        for (int d = 0; d < DH; ++d) acc[d] = acc[d]*corr + p*vt[j][d];
        m = mn;
    }
    __syncthreads();

    // ---- window keys: kpos in [ci*W - W, ci*W + 2W), tiles of 64 ----
    int base = ci*WW - WW;
    for (int t0 = 0; t0 < 3*WW; t0 += 64) {
        for (int i = tid; i < 64*DH; i += 256) {
            int r = i / DH, d2 = i % DH;
            int kp = base + t0 + r;
            bool ok = (kp >= 0 && kp < SS);
            kt[r][d2] = ok ? k[((size_t)(b*SS + kp)*DD + h*DH + d2)] : 0.f;
            vt[r][d2] = ok ? v[((size_t)(b*SS + kp)*DD + h*DH + d2)] : 0.f;
        }
        __syncthreads();
        for (int j = 0; j < 64; ++j) {
            int kp = base + t0 + j;
            int dd = qpos - kp;
            bool valid = (kp >= GG) && (kp < SS) && (dd <= WW) && (dd >= -WW);
            if (valid) {
                float dot = 0.f;
                #pragma unroll
                for (int d = 0; d < DH; ++d) dot += qr[d]*kt[j][d];
                float mn = fmaxf(m, dot);
                float corr = expf(m - mn);
                float p = expf(dot - mn);
                l = l*corr + p;
                #pragma unroll
                for (int d = 0; d < DH; ++d) acc[d] = acc[d]*corr + p*vt[j][d];
                m = mn;
            }
        }
        __syncthreads();
    }

    float invl = 1.0f / l;
    float* cdst = ctx + ((size_t)(b*SS + qpos)*DD + h*DH);
    #pragma unroll
    for (int d = 0; d < DH; ++d) cdst[d] = acc[d]*invl;
}

// ---------------- write global-token ctx rows ----------------
__global__ void k_putg(const float* __restrict__ gctx, float* __restrict__ ctx) {
    int i = blockIdx.x*256 + threadIdx.x;
    if (i >= BB*HN*GG*DH) return;
    int dh = i % DH; int g = (i/DH) % GG; int h = (i/(DH*GG)) % HN; int b = i/(DH*GG*HN);
    ctx[((size_t)(b*SS + g)*DD + h*DH + dh)] = gctx[i];
}

extern "C" void kernel_launch(void* const* d_in, const int* in_sizes, int n_in,
                              void* d_out, int out_size, void* d_ws, size_t ws_size,
                              hipStream_t stream) {
    const int*   ids  = (const int*)  d_in[0];
    const float* emb  = (const float*)d_in[1];
    const float* Wq   = (const float*)d_in[2];
    const float* bq   = (const float*)d_in[3];
    const float* Wk   = (const float*)d_in[4];
    const float* bk   = (const float*)d_in[5];
    const float* Wv   = (const float*)d_in[6];
    const float* bv   = (const float*)d_in[7];
    const float* Wqg  = (const float*)d_in[8];
    const float* bqg  = (const float*)d_in[9];
    const float* Wkg  = (const float*)d_in[10];
    const float* bkg  = (const float*)d_in[11];
    const float* Wvg  = (const float*)d_in[12];
    const float* bvg  = (const float*)d_in[13];
    const float* Wo   = (const float*)d_in[14];
    const float* bo   = (const float*)d_in[15];
    float* out = (float*)d_out;

    const size_t BIG = (size_t)NTOK * DD;           // 6291456 floats
    float* xA   = (float*)d_ws;                      // x, later ctx
    float* bufB = xA + BIG;                          // kg, later q
    float* bufC = bufB + BIG;                        // vg, later k
    float* bufD = bufC + BIG;                        // v
    float* qg   = bufD + BIG;                        // 32*768
    float* gctx = qg + 32*DD;                        // 2*12*16*64

    dim3 gemmGrid(DD/BN, NTOK/BM);                   // (12, 128)

    k_gather<<<NTOK, 256, 0, stream>>>(ids, emb, xA);

    // global projections first (buffers reused afterwards)
    k_gemm<<<gemmGrid, 256, 0, stream>>>(xA, Wkg, bkg, bufB, 1.0f);
    k_gemm<<<gemmGrid, 256, 0, stream>>>(xA, Wvg, bvg, bufC, 1.0f);
    k_qg<<<dim3(DD/64, 32), 64, 0, stream>>>(xA, Wqg, bqg, qg);
    k_gattn<<<BB*HN*GG, 256, 0, stream>>>(qg, bufB, bufC, gctx);

    // regular projections
    k_gemm<<<gemmGrid, 256, 0, stream>>>(xA, Wq, bq, bufB, 0.125f);
    k_gemm<<<gemmGrid, 256, 0, stream>>>(xA, Wk, bk, bufC, 1.0f);
    k_gemm<<<gemmGrid, 256, 0, stream>>>(xA, Wv, bv, bufD, 1.0f);

    // sliding window + global-key attention (ctx overwrites x)
    k_wattn<<<BB*HN*NCHUNK, 256, 0, stream>>>(bufB, bufC, bufD, xA);
    k_putg<<<(BB*HN*GG*DH + 255)/256, 256, 0, stream>>>(gctx, xA);

    // output projection
    k_gemm<<<gemmGrid, 256, 0, stream>>>(xA, Wo, bo, out, 1.0f);
}

// Round 4
// 1272.096 us; speedup vs baseline: 2.1303x; 2.1303x over previous
//
#include <hip/hip_runtime.h>
#include <hip/hip_bf16.h>
#include <math.h>

#define HN 12
#define DH 64
#define WW 256
#define GG 16
#define BB 2
#define SS 4096
#define DD 768
#define NTOK (BB*SS)        // 8192
#define NCHUNK (SS/WW)      // 16

typedef __attribute__((ext_vector_type(8))) short bhalf8;
typedef __attribute__((ext_vector_type(4))) float f32x4;

// ---------------- embedding gather -> bf16 x ----------------
__global__ void k_gather(const int* __restrict__ ids, const float* __restrict__ emb,
                         __hip_bfloat16* __restrict__ x) {
    int row = blockIdx.x;
    int id = ids[row];
    const float4* src = (const float4*)(emb + (size_t)id * DD);
    int j = threadIdx.x;
    if (j < DD/4) {
        float4 f = src[j];
        union { __hip_bfloat16 h[4]; unsigned long long u; } P;
        P.h[0] = __float2bfloat16(f.x);
        P.h[1] = __float2bfloat16(f.y);
        P.h[2] = __float2bfloat16(f.z);
        P.h[3] = __float2bfloat16(f.w);
        *(unsigned long long*)(x + (size_t)row*DD + j*4) = P.u;
    }
}

// ---------------- weight transpose + bf16 convert: Wt[n][k] = bf16(W[k][n]) ----------------
__global__ void k_wtrans(const float* __restrict__ W, __hip_bfloat16* __restrict__ Wt) {
    __shared__ float tile[32][33];
    int tx = threadIdx.x & 31, ty = threadIdx.x >> 5;   // 32x8
    int c0 = blockIdx.x*32, r0 = blockIdx.y*32;
    #pragma unroll
    for (int i = 0; i < 32; i += 8)
        tile[ty+i][tx] = W[(size_t)(r0+ty+i)*DD + c0+tx];
    __syncthreads();
    #pragma unroll
    for (int i = 0; i < 32; i += 8)
        Wt[(size_t)(c0+ty+i)*DD + r0+tx] = __float2bfloat16(tile[tx][ty+i]);
}

// ---------------- bf16 MFMA GEMM: C[M x 768] = A[M x 768] @ Bt^T + bias, * scale ----------------
// A row-major bf16 [M x K], Bt row-major bf16 [N x K] (i.e. W^T), C f32 [M x N]
__global__ __launch_bounds__(256) void k_gemm_bf16(
    const __hip_bfloat16* __restrict__ A, const __hip_bfloat16* __restrict__ Bt,
    const float* __restrict__ bias, float* __restrict__ C, float scale)
{
    const int K = DD, N = DD;
    __shared__ short As[128*32];
    __shared__ short Bs[128*32];
    int tid = threadIdx.x;
    int w = tid >> 6, l = tid & 63;
    int wr = w >> 1, wc = w & 1;
    int lr = l & 15, lg = l >> 4;
    int row0 = blockIdx.y * 128, col0 = blockIdx.x * 128;

    int r_a = tid >> 2;            // staging row (0..63), +64 for second half
    int c8  = (tid & 3) * 8;       // k-offset in bf16 elems

    f32x4 acc[4][4];
    #pragma unroll
    for (int m = 0; m < 4; ++m)
        #pragma unroll
        for (int n = 0; n < 4; ++n)
            acc[m][n] = (f32x4){0.f,0.f,0.f,0.f};

    for (int t = 0; t < K/32; ++t) {
        int k0 = t * 32;
        bhalf8 va0 = *(const bhalf8*)(A  + (size_t)(row0 + r_a)      * K + k0 + c8);
        bhalf8 va1 = *(const bhalf8*)(A  + (size_t)(row0 + r_a + 64) * K + k0 + c8);
        bhalf8 vb0 = *(const bhalf8*)(Bt + (size_t)(col0 + r_a)      * K + k0 + c8);
        bhalf8 vb1 = *(const bhalf8*)(Bt + (size_t)(col0 + r_a + 64) * K + k0 + c8);
        __syncthreads();
        *(bhalf8*)&As[r_a*32 + c8]      = va0;
        *(bhalf8*)&As[(r_a+64)*32 + c8] = va1;
        *(bhalf8*)&Bs[r_a*32 + c8]      = vb0;
        *(bhalf8*)&Bs[(r_a+64)*32 + c8] = vb1;
        __syncthreads();
        bhalf8 af[4], bf[4];
        #pragma unroll
        for (int m = 0; m < 4; ++m)
            af[m] = *(const bhalf8*)&As[(wr*64 + m*16 + lr)*32 + lg*8];
        #pragma unroll
        for (int n = 0; n < 4; ++n)
            bf[n] = *(const bhalf8*)&Bs[(wc*64 + n*16 + lr)*32 + lg*8];
        #pragma unroll
        for (int m = 0; m < 4; ++m)
            #pragma unroll
            for (int n = 0; n < 4; ++n)
                acc[m][n] = __builtin_amdgcn_mfma_f32_16x16x32_bf16(af[m], bf[n], acc[m][n], 0, 0, 0);
    }

    #pragma unroll
    for (int m = 0; m < 4; ++m) {
        #pragma unroll
        for (int n = 0; n < 4; ++n) {
            int col = col0 + wc*64 + n*16 + lr;
            float bcol = bias[col];
            #pragma unroll
            for (int j = 0; j < 4; ++j) {
                int row = row0 + wr*64 + m*16 + lg*4 + j;
                C[(size_t)row*N + col] = (acc[m][n][j] + bcol) * scale;
            }
        }
    }
}

// ---------------- qg projection: 32 rows of x @ Wqg + bqg, *0.125 ----------------
__global__ void k_qg(const __hip_bfloat16* __restrict__ x, const float* __restrict__ Wqg,
                     const float* __restrict__ bqg, float* __restrict__ qg) {
    int col = blockIdx.x * 64 + threadIdx.x;
    int r = blockIdx.y;
    int b = r / GG, g = r % GG;
    const __hip_bfloat16* xr = x + (size_t)(b*SS + g)*DD;
    float acc = 0.f;
    for (int d = 0; d < DD; ++d) acc += __bfloat162float(xr[d]) * Wqg[(size_t)d*DD + col];
    qg[r*DD + col] = (acc + bqg[col]) * 0.125f;
}

// ---------------- global-token full attention ----------------
__global__ __launch_bounds__(256) void k_gattn(const float* __restrict__ qg,
                                               const float* __restrict__ kg,
                                               const float* __restrict__ vg,
                                               float* __restrict__ gctx) {
    int bid = blockIdx.x;
    int b = bid / (HN*GG);
    int h = (bid / GG) % HN;
    int g = bid % GG;
    int tid = threadIdx.x;
    __shared__ float qrow[DH];
    __shared__ float sc[SS];
    __shared__ float red[256];
    __shared__ float part[4][DH];
    if (tid < DH) qrow[tid] = qg[(size_t)(b*GG + g)*DD + h*DH + tid];
    __syncthreads();
    float lmax = -1e30f;
    for (int s = tid; s < SS; s += 256) {
        const float* kr = kg + ((size_t)(b*SS + s)*DD + h*DH);
        float dot = 0.f;
        #pragma unroll
        for (int d = 0; d < DH; ++d) dot += qrow[d]*kr[d];
        sc[s] = dot;
        lmax = fmaxf(lmax, dot);
    }
    red[tid] = lmax; __syncthreads();
    for (int st = 128; st > 0; st >>= 1) { if (tid < st) red[tid] = fmaxf(red[tid], red[tid+st]); __syncthreads(); }
    float m = red[0];
    __syncthreads();
    float lsum = 0.f;
    for (int s = tid; s < SS; s += 256) { float p = expf(sc[s]-m); sc[s] = p; lsum += p; }
    red[tid] = lsum; __syncthreads();
    for (int st = 128; st > 0; st >>= 1) { if (tid < st) red[tid] += red[tid+st]; __syncthreads(); }
    float inv = 1.0f / red[0];
    int dh = tid & 63, s4 = tid >> 6;
    float acc = 0.f;
    for (int s = s4; s < SS; s += 4) acc += sc[s] * vg[((size_t)(b*SS+s)*DD + h*DH + dh)];
    part[s4][dh] = acc;
    __syncthreads();
    if (tid < DH) {
        float r2 = (part[0][tid]+part[1][tid]+part[2][tid]+part[3][tid]) * inv;
        gctx[((size_t)((b*HN + h)*GG + g))*DH + tid] = r2;
    }
}

// ---------------- sliding-window + global-key attention ----------------
// grid: BB*HN*NCHUNK*4 blocks, 256 threads = 64 queries x 4 key-replica waves
__global__ __launch_bounds__(256) void k_wattn(const float* __restrict__ q,
                                               const float* __restrict__ k,
                                               const float* __restrict__ v,
                                               __hip_bfloat16* __restrict__ ctx) {
    int bid = blockIdx.x;
    int qs = bid & 3;
    int rest = bid >> 2;
    int ci = rest % NCHUNK;
    int h  = (rest / NCHUNK) % HN;
    int b  = rest / (NCHUNK*HN);
    int tid = threadIdx.x;
    int qq = tid & 63;          // query within block
    int r  = tid >> 6;          // replica (wave) 0..3
    int qpos = ci*WW + qs*64 + qq;

    __shared__ float smem[2*64*DH];         // kt | vt (accs overlays after tiles)
    __shared__ float mred[4][64], lred[4][64];
    const int VOFF = 64*DH;

    float qr[DH];
    {
        const float4* qsrc = (const float4*)(q + (size_t)(b*SS+qpos)*DD + h*DH);
        #pragma unroll
        for (int i = 0; i < DH/4; ++i) ((float4*)qr)[i] = qsrc[i];
    }

    float m = -1e30f, l = 0.f;
    float acc[DH];
    #pragma unroll
    for (int d = 0; d < DH; ++d) acc[d] = 0.f;

    // ---- global keys 0..15 (unmasked) ----
    {
        for (int i = tid; i < GG*16; i += 256) {
            int rr = i >> 4, d4 = i & 15;
            *(float4*)&smem[rr*DH + d4*4]        = *(const float4*)(k + (size_t)(b*SS+rr)*DD + h*DH + d4*4);
            *(float4*)&smem[VOFF + rr*DH + d4*4] = *(const float4*)(v + (size_t)(b*SS+rr)*DD + h*DH + d4*4);
        }
        __syncthreads();
        for (int jj = 0; jj < 4; ++jj) {
            int j = r*4 + jj;
            float dot = 0.f;
            #pragma unroll
            for (int d = 0; d < DH; ++d) dot += qr[d]*smem[j*DH + d];
            if (dot > m) {
                float corr = __expf(m - dot);
                l *= corr;
                #pragma unroll
                for (int d = 0; d < DH; ++d) acc[d] *= corr;
                m = dot;
            }
            float p = __expf(dot - m);
            l += p;
            #pragma unroll
            for (int d = 0; d < DH; ++d) acc[d] += p * smem[VOFF + j*DH + d];
        }
        __syncthreads();
    }

    // ---- window tiles ----
    int q0 = ci*WW + qs*64;
    int lo = max(GG, q0 - WW);
    int hi = min(SS, q0 + 64 + WW);
    int tb0 = lo & ~63;
    for (int tb = tb0; tb < hi; tb += 64) {
        for (int i = tid; i < 64*16; i += 256) {
            int rr = i >> 4, d4 = i & 15;
            int kp = tb + rr;
            float4 kv, vv;
            if (kp < SS) {
                kv = *(const float4*)(k + (size_t)(b*SS+kp)*DD + h*DH + d4*4);
                vv = *(const float4*)(v + (size_t)(b*SS+kp)*DD + h*DH + d4*4);
            } else {
                kv = make_float4(0.f,0.f,0.f,0.f);
                vv = kv;
            }
            *(float4*)&smem[rr*DH + d4*4] = kv;
            *(float4*)&smem[VOFF + rr*DH + d4*4] = vv;
        }
        __syncthreads();
        for (int jj = 0; jj < 16; ++jj) {
            int j = r*16 + jj;
            int kp = tb + j;
            bool valid = (kp >= GG) && (kp < SS) && (qpos - kp <= WW) && (kp - qpos <= WW);
            if (valid) {
                float dot = 0.f;
                #pragma unroll
                for (int d = 0; d < DH; ++d) dot += qr[d]*smem[j*DH + d];
                if (dot > m) {
                    float corr = __expf(m - dot);
                    l *= corr;
                    #pragma unroll
                    for (int d = 0; d < DH; ++d) acc[d] *= corr;
                    m = dot;
                }
                float p = __expf(dot - m);
                l += p;
                #pragma unroll
                for (int d = 0; d < DH; ++d) acc[d] += p * smem[VOFF + j*DH + d];
            }
        }
        __syncthreads();
    }

    // ---- merge the 4 replica states per query ----
    mred[r][qq] = m; lred[r][qq] = l;
    __syncthreads();
    float M = fmaxf(fmaxf(mred[0][qq], mred[1][qq]), fmaxf(mred[2][qq], mred[3][qq]));
    float L = lred[0][qq]*__expf(mred[0][qq]-M) + lred[1][qq]*__expf(mred[1][qq]-M)
            + lred[2][qq]*__expf(mred[2][qq]-M) + lred[3][qq]*__expf(mred[3][qq]-M);
    float myscale = __expf(m - M);
    // phased accumulate into smem (overlaying kt/vt), stride 65 to dodge bank conflicts
    for (int p = 0; p < 4; ++p) {
        if (r == p) {
            if (p == 0) {
                #pragma unroll
                for (int d = 0; d < DH; ++d) smem[qq*65 + d] = acc[d]*myscale;
            } else {
                #pragma unroll
                for (int d = 0; d < DH; ++d) smem[qq*65 + d] += acc[d]*myscale;
            }
        }
        __syncthreads();
    }
    float inv = 1.0f / L;
    __hip_bfloat16* dst = ctx + (size_t)(b*SS+qpos)*DD + h*DH;
    for (int d = r*16; d < r*16+16; ++d)
        dst[d] = __float2bfloat16(smem[qq*65 + d] * inv);
}

// ---------------- write global-token ctx rows (bf16) ----------------
__global__ void k_putg(const float* __restrict__ gctx, __hip_bfloat16* __restrict__ ctx) {
    int i = blockIdx.x*256 + threadIdx.x;
    if (i >= BB*HN*GG*DH) return;
    int dh = i % DH; int g = (i/DH) % GG; int h = (i/(DH*GG)) % HN; int b = i/(DH*GG*HN);
    ctx[((size_t)(b*SS + g)*DD + h*DH + dh)] = __float2bfloat16(gctx[i]);
}

extern "C" void kernel_launch(void* const* d_in, const int* in_sizes, int n_in,
                              void* d_out, int out_size, void* d_ws, size_t ws_size,
                              hipStream_t stream) {
    const int*   ids  = (const int*)  d_in[0];
    const float* emb  = (const float*)d_in[1];
    const float* Wq   = (const float*)d_in[2];
    const float* bq   = (const float*)d_in[3];
    const float* Wk   = (const float*)d_in[4];
    const float* bk   = (const float*)d_in[5];
    const float* Wv   = (const float*)d_in[6];
    const float* bv   = (const float*)d_in[7];
    const float* Wqg  = (const float*)d_in[8];
    const float* bqg  = (const float*)d_in[9];
    const float* Wkg  = (const float*)d_in[10];
    const float* bkg  = (const float*)d_in[11];
    const float* Wvg  = (const float*)d_in[12];
    const float* bvg  = (const float*)d_in[13];
    const float* Wo   = (const float*)d_in[14];
    const float* bo   = (const float*)d_in[15];
    float* out = (float*)d_out;

    const size_t BIG = (size_t)NTOK * DD;
    const size_t WSZ = (size_t)DD * DD;
    __hip_bfloat16* xbf = (__hip_bfloat16*)d_ws;      // x, later ctx (aliased)
    __hip_bfloat16* Wt  = xbf + BIG;                  // 6 transposed bf16 weights
    float* qb  = (float*)(Wt + 6*WSZ);                // kg, later q
    float* kb  = qb + BIG;                            // vg, later k
    float* vb  = kb + BIG;                            // v
    float* qg  = vb + BIG;
    float* gctx = qg + 32*DD;

    __hip_bfloat16* WqT  = Wt + 0*WSZ;
    __hip_bfloat16* WkT  = Wt + 1*WSZ;
    __hip_bfloat16* WvT  = Wt + 2*WSZ;
    __hip_bfloat16* WkgT = Wt + 3*WSZ;
    __hip_bfloat16* WvgT = Wt + 4*WSZ;
    __hip_bfloat16* WoT  = Wt + 5*WSZ;

    dim3 tg(DD/32, DD/32);
    k_gather<<<NTOK, 256, 0, stream>>>(ids, emb, xbf);
    k_wtrans<<<tg, 256, 0, stream>>>(Wq,  WqT);
    k_wtrans<<<tg, 256, 0, stream>>>(Wk,  WkT);
    k_wtrans<<<tg, 256, 0, stream>>>(Wv,  WvT);
    k_wtrans<<<tg, 256, 0, stream>>>(Wkg, WkgT);
    k_wtrans<<<tg, 256, 0, stream>>>(Wvg, WvgT);
    k_wtrans<<<tg, 256, 0, stream>>>(Wo,  WoT);

    dim3 gemmGrid(DD/128, NTOK/128);                  // (6, 64)

    // global projections (into qb/kb, consumed by gattn before being reused)
    k_gemm_bf16<<<gemmGrid, 256, 0, stream>>>(xbf, WkgT, bkg, qb, 1.0f);
    k_gemm_bf16<<<gemmGrid, 256, 0, stream>>>(xbf, WvgT, bvg, kb, 1.0f);
    k_qg<<<dim3(DD/64, 32), 64, 0, stream>>>(xbf, Wqg, bqg, qg);
    k_gattn<<<BB*HN*GG, 256, 0, stream>>>(qg, qb, kb, gctx);

    // regular projections
    k_gemm_bf16<<<gemmGrid, 256, 0, stream>>>(xbf, WqT, bq, qb, 0.125f);
    k_gemm_bf16<<<gemmGrid, 256, 0, stream>>>(xbf, WkT, bk, kb, 1.0f);
    k_gemm_bf16<<<gemmGrid, 256, 0, stream>>>(xbf, WvT, bv, vb, 1.0f);

    // sliding window + global-key attention (ctx bf16 overwrites x)
    k_wattn<<<BB*HN*NCHUNK*4, 256, 0, stream>>>(qb, kb, vb, xbf);
    k_putg<<<(BB*HN*GG*DH + 255)/256, 256, 0, stream>>>(gctx, xbf);

    // output projection
    k_gemm_bf16<<<gemmGrid, 256, 0, stream>>>(xbf, WoT, bo, out, 1.0f);
}

// Round 6
// 813.369 us; speedup vs baseline: 3.3318x; 1.5640x over previous
//
#include <hip/hip_runtime.h>
#include <hip/hip_bf16.h>
#include <math.h>

#define HN 12
#define DH 64
#define WW 256
#define GG 16
#define BB 2
#define SS 4096
#define DD 768
#define NTOK (BB*SS)        // 8192
#define NCHUNK (SS/WW)      // 16
#define QKVS 2304
#define KGS 1536

typedef __attribute__((ext_vector_type(8))) short bhalf8;
typedef __attribute__((ext_vector_type(4))) float f32x4;

__device__ __forceinline__ int swzb(int row, int colbyte) {
    // 128-byte rows; XOR-swizzle bits 4-6 by row&7 (T2) -> conflict-free b128 col reads
    return row*128 + (colbyte ^ ((row & 7) << 4));
}
__device__ __forceinline__ float bf2f(ushort u) {
    union { unsigned int i; float f; } x; x.i = ((unsigned int)u) << 16; return x.f;
}

// ---------------- embedding gather -> bf16 x ----------------
__global__ void k_gather(const int* __restrict__ ids, const float* __restrict__ emb,
                         __hip_bfloat16* __restrict__ x) {
    int row = blockIdx.x;
    int id = ids[row];
    const float4* src = (const float4*)(emb + (size_t)id * DD);
    int j = threadIdx.x;
    if (j < DD/4) {
        float4 f = src[j];
        union { __hip_bfloat16 h[4]; unsigned long long u; } P;
        P.h[0] = __float2bfloat16(f.x);
        P.h[1] = __float2bfloat16(f.y);
        P.h[2] = __float2bfloat16(f.z);
        P.h[3] = __float2bfloat16(f.w);
        *(unsigned long long*)(x + (size_t)row*DD + j*4) = P.u;
    }
}

// ---------------- weight transpose + bf16 convert + scale ----------------
__global__ void k_wtrans(const float* __restrict__ W, __hip_bfloat16* __restrict__ Wt,
                         float scale) {
    __shared__ float tile[32][33];
    int tx = threadIdx.x & 31, ty = threadIdx.x >> 5;   // 32x8
    int c0 = blockIdx.x*32, r0 = blockIdx.y*32;
    #pragma unroll
    for (int i = 0; i < 32; i += 8)
        tile[ty+i][tx] = W[(size_t)(r0+ty+i)*DD + c0+tx];
    __syncthreads();
    #pragma unroll
    for (int i = 0; i < 32; i += 8)
        Wt[(size_t)(c0+ty+i)*DD + r0+tx] = __float2bfloat16(tile[tx][ty+i] * scale);
}

// ---------------- bias concat: [bq*0.125 | bk | bv | bkg | bvg] ----------------
__global__ void k_bcat(const float* __restrict__ bq, const float* __restrict__ bk,
                       const float* __restrict__ bv, const float* __restrict__ bkg,
                       const float* __restrict__ bvg, float* __restrict__ bc) {
    int i = blockIdx.x*256 + threadIdx.x;
    if (i >= 3840) return;
    float v;
    if (i < 768) v = bq[i] * 0.125f;
    else if (i < 1536) v = bk[i-768];
    else if (i < 2304) v = bv[i-1536];
    else if (i < 3072) v = bkg[i-2304];
    else v = bvg[i-3072];
    bc[i] = v;
}

// ---------------- MFMA GEMM, bf16 out: C[M x N] = A[M x 768] @ Bt^T + bias ----------------
__global__ __launch_bounds__(256) void k_gemm_nt(
    const __hip_bfloat16* __restrict__ A, const __hip_bfloat16* __restrict__ Bt,
    const float* __restrict__ bias, __hip_bfloat16* __restrict__ C, int N)
{
    const int K = DD;
    __shared__ short As[128*32];
    __shared__ short Bs[128*32];
    int tid = threadIdx.x;
    int w = tid >> 6, l = tid & 63;
    int wr = w >> 1, wc = w & 1;
    int lr = l & 15, lg = l >> 4;
    int row0 = blockIdx.y * 128, col0 = blockIdx.x * 128;
    int r_a = tid >> 2;
    int c8  = (tid & 3) * 8;

    f32x4 acc[4][4];
    #pragma unroll
    for (int m = 0; m < 4; ++m)
        #pragma unroll
        for (int n = 0; n < 4; ++n)
            acc[m][n] = (f32x4){0.f,0.f,0.f,0.f};

    for (int t = 0; t < K/32; ++t) {
        int k0 = t * 32;
        bhalf8 va0 = *(const bhalf8*)(A  + (size_t)(row0 + r_a)      * K + k0 + c8);
        bhalf8 va1 = *(const bhalf8*)(A  + (size_t)(row0 + r_a + 64) * K + k0 + c8);
        bhalf8 vb0 = *(const bhalf8*)(Bt + (size_t)(col0 + r_a)      * K + k0 + c8);
        bhalf8 vb1 = *(const bhalf8*)(Bt + (size_t)(col0 + r_a + 64) * K + k0 + c8);
        __syncthreads();
        *(bhalf8*)&As[r_a*32 + c8]      = va0;
        *(bhalf8*)&As[(r_a+64)*32 + c8] = va1;
        *(bhalf8*)&Bs[r_a*32 + c8]      = vb0;
        *(bhalf8*)&Bs[(r_a+64)*32 + c8] = vb1;
        __syncthreads();
        bhalf8 af[4], bf[4];
        #pragma unroll
        for (int m = 0; m < 4; ++m)
            af[m] = *(const bhalf8*)&As[(wr*64 + m*16 + lr)*32 + lg*8];
        #pragma unroll
        for (int n = 0; n < 4; ++n)
            bf[n] = *(const bhalf8*)&Bs[(wc*64 + n*16 + lr)*32 + lg*8];
        #pragma unroll
        for (int m = 0; m < 4; ++m)
            #pragma unroll
            for (int n = 0; n < 4; ++n)
                acc[m][n] = __builtin_amdgcn_mfma_f32_16x16x32_bf16(af[m], bf[n], acc[m][n], 0, 0, 0);
    }

    #pragma unroll
    for (int m = 0; m < 4; ++m) {
        #pragma unroll
        for (int n = 0; n < 4; ++n) {
            int col = col0 + wc*64 + n*16 + lr;
            float bcol = bias[col];
            #pragma unroll
            for (int j = 0; j < 4; ++j) {
                int row = row0 + wr*64 + m*16 + lg*4 + j;
                C[(size_t)row*N + col] = __float2bfloat16(acc[m][n][j] + bcol);
            }
        }
    }
}

// ---------------- MFMA GEMM, f32 out (final Wo) ----------------
__global__ __launch_bounds__(256) void k_gemm_f32(
    const __hip_bfloat16* __restrict__ A, const __hip_bfloat16* __restrict__ Bt,
    const float* __restrict__ bias, float* __restrict__ C)
{
    const int K = DD, N = DD;
    __shared__ short As[128*32];
    __shared__ short Bs[128*32];
    int tid = threadIdx.x;
    int w = tid >> 6, l = tid & 63;
    int wr = w >> 1, wc = w & 1;
    int lr = l & 15, lg = l >> 4;
    int row0 = blockIdx.y * 128, col0 = blockIdx.x * 128;
    int r_a = tid >> 2;
    int c8  = (tid & 3) * 8;

    f32x4 acc[4][4];
    #pragma unroll
    for (int m = 0; m < 4; ++m)
        #pragma unroll
        for (int n = 0; n < 4; ++n)
            acc[m][n] = (f32x4){0.f,0.f,0.f,0.f};

    for (int t = 0; t < K/32; ++t) {
        int k0 = t * 32;
        bhalf8 va0 = *(const bhalf8*)(A  + (size_t)(row0 + r_a)      * K + k0 + c8);
        bhalf8 va1 = *(const bhalf8*)(A  + (size_t)(row0 + r_a + 64) * K + k0 + c8);
        bhalf8 vb0 = *(const bhalf8*)(Bt + (size_t)(col0 + r_a)      * K + k0 + c8);
        bhalf8 vb1 = *(const bhalf8*)(Bt + (size_t)(col0 + r_a + 64) * K + k0 + c8);
        __syncthreads();
        *(bhalf8*)&As[r_a*32 + c8]      = va0;
        *(bhalf8*)&As[(r_a+64)*32 + c8] = va1;
        *(bhalf8*)&Bs[r_a*32 + c8]      = vb0;
        *(bhalf8*)&Bs[(r_a+64)*32 + c8] = vb1;
        __syncthreads();
        bhalf8 af[4], bf[4];
        #pragma unroll
        for (int m = 0; m < 4; ++m)
            af[m] = *(const bhalf8*)&As[(wr*64 + m*16 + lr)*32 + lg*8];
        #pragma unroll
        for (int n = 0; n < 4; ++n)
            bf[n] = *(const bhalf8*)&Bs[(wc*64 + n*16 + lr)*32 + lg*8];
        #pragma unroll
        for (int m = 0; m < 4; ++m)
            #pragma unroll
            for (int n = 0; n < 4; ++n)
                acc[m][n] = __builtin_amdgcn_mfma_f32_16x16x32_bf16(af[m], bf[n], acc[m][n], 0, 0, 0);
    }

    #pragma unroll
    for (int m = 0; m < 4; ++m) {
        #pragma unroll
        for (int n = 0; n < 4; ++n) {
            int col = col0 + wc*64 + n*16 + lr;
            float bcol = bias[col];
            #pragma unroll
            for (int j = 0; j < 4; ++j) {
                int row = row0 + wr*64 + m*16 + lg*4 + j;
                C[(size_t)row*N + col] = acc[m][n][j] + bcol;
            }
        }
    }
}

// ---------------- qg projection ----------------
__global__ void k_qg(const __hip_bfloat16* __restrict__ x, const float* __restrict__ Wqg,
                     const float* __restrict__ bqg, float* __restrict__ qg) {
    int col = blockIdx.x * 64 + threadIdx.x;
    int r = blockIdx.y;
    int b = r / GG, g = r % GG;
    const __hip_bfloat16* xr = x + (size_t)(b*SS + g)*DD;
    float acc = 0.f;
    for (int d = 0; d < DD; ++d) acc += __bfloat162float(xr[d]) * Wqg[(size_t)d*DD + col];
    qg[r*DD + col] = (acc + bqg[col]) * 0.125f;
}

// ---------------- global-token full attention (bf16 kgvg) ----------------
__global__ __launch_bounds__(256) void k_gattn(const float* __restrict__ qg,
                                               const __hip_bfloat16* __restrict__ kgvg,
                                               float* __restrict__ gctx) {
    int bid = blockIdx.x;
    int b = bid / (HN*GG);
    int h = (bid / GG) % HN;
    int g = bid % GG;
    int tid = threadIdx.x;
    __shared__ float qrow[DH];
    __shared__ float sc[SS];
    __shared__ float red[256];
    __shared__ float part[4][DH];
    if (tid < DH) qrow[tid] = qg[(size_t)(b*GG + g)*DD + h*DH + tid];
    __syncthreads();
    float lmax = -1e30f;
    for (int s = tid; s < SS; s += 256) {
        const bhalf8* kr = (const bhalf8*)(kgvg + (size_t)(b*SS + s)*KGS + h*DH);
        float dot = 0.f;
        #pragma unroll
        for (int c = 0; c < 8; ++c) {
            bhalf8 kv = kr[c];
            #pragma unroll
            for (int i = 0; i < 8; ++i) dot += qrow[c*8+i] * bf2f((ushort)kv[i]);
        }
        sc[s] = dot;
        lmax = fmaxf(lmax, dot);
    }
    red[tid] = lmax; __syncthreads();
    for (int st = 128; st > 0; st >>= 1) { if (tid < st) red[tid] = fmaxf(red[tid], red[tid+st]); __syncthreads(); }
    float m = red[0];
    __syncthreads();
    float lsum = 0.f;
    for (int s = tid; s < SS; s += 256) { float p = __expf(sc[s]-m); sc[s] = p; lsum += p; }
    red[tid] = lsum; __syncthreads();
    for (int st = 128; st > 0; st >>= 1) { if (tid < st) red[tid] += red[tid+st]; __syncthreads(); }
    float inv = 1.0f / red[0];
    int dh = tid & 63, s4 = tid >> 6;
    float acc = 0.f;
    for (int s = s4; s < SS; s += 4)
        acc += sc[s] * bf2f(*(const ushort*)(kgvg + (size_t)(b*SS+s)*KGS + DD + h*DH + dh));
    part[s4][dh] = acc;
    __syncthreads();
    if (tid < DH) {
        float r2 = (part[0][tid]+part[1][tid]+part[2][tid]+part[3][tid]) * inv;
        gctx[((size_t)((b*HN + h)*GG + g))*DH + tid] = r2;
    }
}

// ---------------- MFMA sliding-window + global-key flash attention ----------------
// grid: BB*HN*32 blocks (128 queries each), 256 threads = 4 waves x 32 queries
__global__ __launch_bounds__(256) void k_wattn(const __hip_bfloat16* __restrict__ qkv,
                                               __hip_bfloat16* __restrict__ ctx) {
    __shared__ ushort lds[16384];       // K:[0,4096) Vt:[4096,8192) P: 8192 + w*2048
    ushort* Kl = lds;
    ushort* Vl = lds + 4096;

    int bid = blockIdx.x;
    int ci2 = bid & 31;
    int h   = (bid >> 5) % HN;
    int b   = bid / (32*HN);
    int q0  = ci2 * 128;
    int tid = threadIdx.x;
    int w = tid >> 6, l = tid & 63;
    int lr = l & 15, lg = l >> 4;
    int qw0 = q0 + w*32;
    ushort* Pl = lds + 8192 + w*2048;

    const __hip_bfloat16* qbase = qkv + (size_t)(b*SS)*QKVS + h*DH;
    const __hip_bfloat16* kbase = qbase + DD;
    const __hip_bfloat16* vbase = qbase + 2*DD;

    // Q fragments (A-operand): row = qw0+mf*16+lr, k-cols ks*32+lg*8
    bhalf8 aq[2][2];
    #pragma unroll
    for (int mf = 0; mf < 2; ++mf) {
        int qp = qw0 + mf*16 + lr;
        #pragma unroll
        for (int ks = 0; ks < 2; ++ks)
            aq[mf][ks] = *(const bhalf8*)(qbase + (size_t)qp*QKVS + ks*32 + lg*8);
    }

    f32x4 accO[2][4];
    float mrow[2][4], lrow[2][4];
    #pragma unroll
    for (int mf = 0; mf < 2; ++mf) {
        #pragma unroll
        for (int nf = 0; nf < 4; ++nf) accO[mf][nf] = (f32x4){0.f,0.f,0.f,0.f};
        #pragma unroll
        for (int r = 0; r < 4; ++r) { mrow[mf][r] = -1e30f; lrow[mf][r] = 0.f; }
    }

    int kr = tid >> 3;              // K stage: row 0..31 (+32), colbyte (tid&7)*16
    int kc = (tid & 7) * 16;
    int vp = (tid & 31) * 2;        // V stage: kp pair base 0..62
    int vc = tid >> 5;              // d-octet 0..7

    int tb_lo = max(64, q0 - 256);
    int hi = min(SS, q0 + 384);

    for (int tb = 0; tb < hi; tb = (tb == 0 ? tb_lo : tb + 64)) {
        __syncthreads();
        // ---- stage K tile [64 keys][64 d] (swizzled rows) ----
        {
            bhalf8 k0 = *(const bhalf8*)(kbase + (size_t)(tb+kr)*QKVS + (kc>>1));
            bhalf8 k1 = *(const bhalf8*)(kbase + (size_t)(tb+kr+32)*QKVS + (kc>>1));
            *(bhalf8*)((char*)Kl + swzb(kr, kc))    = k0;
            *(bhalf8*)((char*)Kl + swzb(kr+32, kc)) = k1;
            // ---- stage V^T tile [64 d][64 keys]: pack kp-pairs as u32 ----
            bhalf8 v0 = *(const bhalf8*)(vbase + (size_t)(tb+vp)*QKVS + vc*8);
            bhalf8 v1 = *(const bhalf8*)(vbase + (size_t)(tb+vp+1)*QKVS + vc*8);
            #pragma unroll
            for (int i = 0; i < 8; ++i) {
                int d = vc*8 + i;
                unsigned int val = (unsigned short)v0[i] | ((unsigned int)(unsigned short)v1[i] << 16);
                *(unsigned int*)((char*)Vl + swzb(d, vp*2)) = val;
            }
        }
        __syncthreads();

        if (tb != 0 && (tb < qw0 - 319 || tb > qw0 + 287)) continue;  // wave out of range

        // ---- QK^T: S[32q][64k] ----
        f32x4 accS[2][4];
        #pragma unroll
        for (int mf = 0; mf < 2; ++mf)
            #pragma unroll
            for (int nf = 0; nf < 4; ++nf) accS[mf][nf] = (f32x4){0.f,0.f,0.f,0.f};
        #pragma unroll
        for (int ks = 0; ks < 2; ++ks) {
            bhalf8 bk[4];
            #pragma unroll
            for (int nf = 0; nf < 4; ++nf)
                bk[nf] = *(const bhalf8*)((char*)Kl + swzb(nf*16 + lr, ks*64 + lg*16));
            #pragma unroll
            for (int mf = 0; mf < 2; ++mf)
                #pragma unroll
                for (int nf = 0; nf < 4; ++nf)
                    accS[mf][nf] = __builtin_amdgcn_mfma_f32_16x16x32_bf16(aq[mf][ks], bk[nf], accS[mf][nf], 0, 0, 0);
        }

        // ---- mask (edge tiles only): valid = kp<16 (global) or |q-kp|<=256 ----
        bool full = (tb >= 64) && (tb >= qw0 - 225) && (tb <= qw0 + 193);
        if (!full) {
            #pragma unroll
            for (int nf = 0; nf < 4; ++nf) {
                int kp = tb + nf*16 + lr;
                #pragma unroll
                for (int mf = 0; mf < 2; ++mf)
                    #pragma unroll
                    for (int r = 0; r < 4; ++r) {
                        int qp = qw0 + mf*16 + lg*4 + r;
                        int dd = qp - kp;
                        bool vld = (kp < GG) || (dd <= WW && dd >= -WW);
                        if (!vld) accS[mf][nf][r] = -1e9f;
                    }
            }
        }

        // ---- online softmax (rows spread over 16-lane groups) ----
        float corr[2][4], rs[2][4];
        #pragma unroll
        for (int mf = 0; mf < 2; ++mf)
            #pragma unroll
            for (int r = 0; r < 4; ++r) {
                float mx = fmaxf(fmaxf(accS[mf][0][r], accS[mf][1][r]),
                                 fmaxf(accS[mf][2][r], accS[mf][3][r]));
                mx = fmaxf(mx, __shfl_xor(mx, 1));
                mx = fmaxf(mx, __shfl_xor(mx, 2));
                mx = fmaxf(mx, __shfl_xor(mx, 4));
                mx = fmaxf(mx, __shfl_xor(mx, 8));
                float mn = fmaxf(mrow[mf][r], mx);
                corr[mf][r] = __expf(mrow[mf][r] - mn);
                mrow[mf][r] = mn;
                rs[mf][r] = 0.f;
            }
        #pragma unroll
        for (int mf = 0; mf < 2; ++mf)
            #pragma unroll
            for (int nf = 0; nf < 4; ++nf)
                #pragma unroll
                for (int r = 0; r < 4; ++r) {
                    float p = __expf(accS[mf][nf][r] - mrow[mf][r]);
                    accS[mf][nf][r] = p;
                    rs[mf][r] += p;
                }
        #pragma unroll
        for (int mf = 0; mf < 2; ++mf)
            #pragma unroll
            for (int r = 0; r < 4; ++r) {
                float s = rs[mf][r];
                s += __shfl_xor(s, 1);
                s += __shfl_xor(s, 2);
                s += __shfl_xor(s, 4);
                s += __shfl_xor(s, 8);
                lrow[mf][r] = lrow[mf][r] * corr[mf][r] + s;
            }
        #pragma unroll
        for (int mf = 0; mf < 2; ++mf)
            #pragma unroll
            for (int nf = 0; nf < 4; ++nf)
                #pragma unroll
                for (int r = 0; r < 4; ++r)
                    accO[mf][nf][r] *= corr[mf][r];

        // ---- P -> LDS (bf16, swizzled) ----
        #pragma unroll
        for (int mf = 0; mf < 2; ++mf)
            #pragma unroll
            for (int nf = 0; nf < 4; ++nf)
                #pragma unroll
                for (int r = 0; r < 4; ++r) {
                    int q  = mf*16 + lg*4 + r;      // 0..31
                    int ky = nf*16 + lr;            // 0..63
                    *(__hip_bfloat16*)((char*)Pl + swzb(q, ky*2)) = __float2bfloat16(accS[mf][nf][r]);
                }
        asm volatile("s_waitcnt lgkmcnt(0)" ::: "memory");
        __builtin_amdgcn_sched_barrier(0);

        // ---- PV: O += P[32q x 64k] @ V[64k x 64d] ----
        #pragma unroll
        for (int ks = 0; ks < 2; ++ks) {
            bhalf8 ap[2], bv[4];
            #pragma unroll
            for (int mf = 0; mf < 2; ++mf)
                ap[mf] = *(const bhalf8*)((char*)Pl + swzb(mf*16 + lr, ks*64 + lg*16));
            #pragma unroll
            for (int nf = 0; nf < 4; ++nf)
                bv[nf] = *(const bhalf8*)((char*)Vl + swzb(nf*16 + lr, ks*64 + lg*16));
            #pragma unroll
            for (int mf = 0; mf < 2; ++mf)
                #pragma unroll
                for (int nf = 0; nf < 4; ++nf)
                    accO[mf][nf] = __builtin_amdgcn_mfma_f32_16x16x32_bf16(ap[mf], bv[nf], accO[mf][nf], 0, 0, 0);
        }
    }

    // ---- write O/l -> ctx (bf16) ----
    #pragma unroll
    for (int mf = 0; mf < 2; ++mf)
        #pragma unroll
        for (int r = 0; r < 4; ++r) {
            int qp = qw0 + mf*16 + lg*4 + r;
            float inv = 1.0f / lrow[mf][r];
            __hip_bfloat16* dst = ctx + (size_t)(b*SS+qp)*DD + h*DH;
            #pragma unroll
            for (int nf = 0; nf < 4; ++nf)
                dst[nf*16 + lr] = __float2bfloat16(accO[mf][nf][r] * inv);
        }
}

// ---------------- write global-token ctx rows (bf16) ----------------
__global__ void k_putg(const float* __restrict__ gctx, __hip_bfloat16* __restrict__ ctx) {
    int i = blockIdx.x*256 + threadIdx.x;
    if (i >= BB*HN*GG*DH) return;
    int dh = i % DH; int g = (i/DH) % GG; int h = (i/(DH*GG)) % HN; int b = i/(DH*GG*HN);
    ctx[((size_t)(b*SS + g)*DD + h*DH + dh)] = __float2bfloat16(gctx[i]);
}

extern "C" void kernel_launch(void* const* d_in, const int* in_sizes, int n_in,
                              void* d_out, int out_size, void* d_ws, size_t ws_size,
                              hipStream_t stream) {
    const int*   ids  = (const int*)  d_in[0];
    const float* emb  = (const float*)d_in[1];
    const float* Wq   = (const float*)d_in[2];
    const float* bq   = (const float*)d_in[3];
    const float* Wk   = (const float*)d_in[4];
    const float* bk   = (const float*)d_in[5];
    const float* Wv   = (const float*)d_in[6];
    const float* bv   = (const float*)d_in[7];
    const float* Wqg  = (const float*)d_in[8];
    const float* bqg  = (const float*)d_in[9];
    const float* Wkg  = (const float*)d_in[10];
    const float* bkg  = (const float*)d_in[11];
    const float* Wvg  = (const float*)d_in[12];
    const float* bvg  = (const float*)d_in[13];
    const float* Wo   = (const float*)d_in[14];
    const float* bo   = (const float*)d_in[15];
    float* out = (float*)d_out;

    const size_t BIG = (size_t)NTOK * DD;
    const size_t WSZ = (size_t)DD * DD;
    __hip_bfloat16* xbf    = (__hip_bfloat16*)d_ws;        // x, later ctx
    __hip_bfloat16* qkv    = xbf + BIG;                    // [8192][2304]
    __hip_bfloat16* kgvg   = qkv + (size_t)NTOK*QKVS;      // [8192][1536]
    __hip_bfloat16* WqkvT  = kgvg + (size_t)NTOK*KGS;      // [2304][768]
    __hip_bfloat16* WkgvgT = WqkvT + 3*WSZ;                // [1536][768]
    __hip_bfloat16* WoT    = WkgvgT + 2*WSZ;               // [768][768]
    float* biasc = (float*)(WoT + WSZ);                    // 3840
    float* qg    = biasc + 3840;                           // 32*768
    float* gctx  = qg + 32*DD;                             // 24576

    dim3 tg(DD/32, DD/32);
    k_gather<<<NTOK, 256, 0, stream>>>(ids, emb, xbf);
    k_wtrans<<<tg, 256, 0, stream>>>(Wq,  WqkvT + 0*WSZ, 0.125f);
    k_wtrans<<<tg, 256, 0, stream>>>(Wk,  WqkvT + 1*WSZ, 1.0f);
    k_wtrans<<<tg, 256, 0, stream>>>(Wv,  WqkvT + 2*WSZ, 1.0f);
    k_wtrans<<<tg, 256, 0, stream>>>(Wkg, WkgvgT + 0*WSZ, 1.0f);
    k_wtrans<<<tg, 256, 0, stream>>>(Wvg, WkgvgT + 1*WSZ, 1.0f);
    k_wtrans<<<tg, 256, 0, stream>>>(Wo,  WoT, 1.0f);
    k_bcat<<<15, 256, 0, stream>>>(bq, bk, bv, bkg, bvg, biasc);

    // fused projections
    k_gemm_nt<<<dim3(QKVS/128, NTOK/128), 256, 0, stream>>>(xbf, WqkvT, biasc, qkv, QKVS);
    k_gemm_nt<<<dim3(KGS/128,  NTOK/128), 256, 0, stream>>>(xbf, WkgvgT, biasc + QKVS, kgvg, KGS);

    // global-token attention
    k_qg<<<dim3(DD/64, 32), 64, 0, stream>>>(xbf, Wqg, bqg, qg);
    k_gattn<<<BB*HN*GG, 256, 0, stream>>>(qg, kgvg, gctx);

    // sliding-window + global-key attention (ctx overwrites xbf)
    k_wattn<<<BB*HN*32, 256, 0, stream>>>(qkv, xbf);
    k_putg<<<(BB*HN*GG*DH + 255)/256, 256, 0, stream>>>(gctx, xbf);

    // output projection
    k_gemm_f32<<<dim3(DD/128, NTOK/128), 256, 0, stream>>>(xbf, WoT, bo, out);
}